// Round 1
// baseline (1629.273 us; speedup 1.0000x reference)
//
#include <hip/hip_runtime.h>
#include <stdint.h>

#define NPIX 16384
#define IMW 128
#define NIMG 8
#define DLV_NONE 0xFFu
#define DLV_ALIVE 0xFEu

// ---------------- prep: levels ----------------
__global__ __launch_bounds__(256) void prep_kernel(const float* __restrict__ model_output,
                                                   const float* __restrict__ labels,
                                                   uint8_t* __restrict__ lvl,
                                                   int* __restrict__ maxL)
{
    int img = blockIdx.x;
    int tid = threadIdx.x;
    bool ismask = img < 4;
    int b = ismask ? img : img - 4;
    const float* src = ismask ? (labels + (size_t)b * NPIX) : (model_output + (size_t)b * NPIX);

    __shared__ float red[32];
    float mn = 0.f, mx = 1.f;
    if (!ismask) {
        float lmn = 1e30f, lmx = -1e30f;
        for (int i = tid; i < NPIX; i += 256) {
            float s = 1.0f / (1.0f + expf(-src[i]));
            lmn = fminf(lmn, s); lmx = fmaxf(lmx, s);
        }
        for (int off = 32; off > 0; off >>= 1) {
            lmn = fminf(lmn, __shfl_down(lmn, off));
            lmx = fmaxf(lmx, __shfl_down(lmx, off));
        }
        int wv = tid >> 6;
        if ((tid & 63) == 0) { red[wv] = lmn; red[8 + wv] = lmx; }
        __syncthreads();
        if (tid == 0) {
            float a = red[0], c = red[8];
            for (int w = 1; w < 4; ++w) { a = fminf(a, red[w]); c = fmaxf(c, red[8 + w]); }
            red[16] = a; red[17] = c;
        }
        __syncthreads();
        mn = red[16]; mx = red[17];
    }
    float denom = mx - mn;
    if (denom <= 0.f) denom = 1.f;

    int lmax = 0;
    for (int i = tid; i < NPIX; i += 256) {
        float q;
        if (ismask) {
            q = src[i] * 10.0f;                 // round(m*10)
        } else {
            float s = 1.0f / (1.0f + expf(-src[i]));
            float t = (s - mn) / denom;         // (pred-mn)/(mx-mn)
            q = t * 10.0f;
        }
        int L = (int)rintf(q);                  // round-half-even, matches jnp.round
        lvl[(size_t)img * NPIX + i] = (uint8_t)L;
        lmax = max(lmax, L);
    }
    for (int off = 32; off > 0; off >>= 1) lmax = max(lmax, __shfl_down(lmax, off));
    __shared__ int redi[8];
    int wv = tid >> 6;
    if ((tid & 63) == 0) redi[wv] = lmax;
    __syncthreads();
    if (tid == 0) {
        int m = redi[0];
        for (int w = 1; w < 4; ++w) m = max(m, redi[w]);
        maxL[img] = m;
    }
}

// ---------------- union-find helpers (par holds KEY of parent; key = (lvl<<14)|idx) ----------------
__device__ inline unsigned uf_find(volatile unsigned* par, unsigned idx)
{
    unsigned k = par[idx];
    for (;;) {
        unsigned j = k & 16383u;
        unsigned pk = par[j];
        if (pk == k) return k;
        k = pk;
    }
}

__device__ inline void uf_union(volatile unsigned* par, unsigned a, unsigned b)
{
    unsigned ka = uf_find(par, a);
    unsigned kb = uf_find(par, b);
    while (ka != kb) {
        unsigned hi = (ka > kb) ? ka : kb;
        unsigned lo = (ka > kb) ? kb : ka;
        unsigned old = atomicCAS((unsigned*)(par + (hi & 16383u)), hi, lo);
        if (old == hi) return;
        ka = uf_find(par, hi & 16383u);
        kb = uf_find(par, lo & 16383u);
    }
}

// ---------------- persistence + top-256 per image ----------------
__global__ __launch_bounds__(1024) void persist_kernel(const uint8_t* __restrict__ lvl_all,
                                                       uint8_t* __restrict__ dlv_all,
                                                       unsigned* __restrict__ par_all,
                                                       unsigned long long* __restrict__ key_all,
                                                       const int* __restrict__ maxL_all,
                                                       float* __restrict__ outP,
                                                       float* __restrict__ outB,
                                                       float* __restrict__ outD)
{
    int img = blockIdx.x;
    int tid = threadIdx.x;
    const uint8_t* lv = lvl_all + (size_t)img * NPIX;
    uint8_t* dlv = dlv_all + (size_t)img * NPIX;
    volatile unsigned* par = par_all + (size_t)img * NPIX;
    unsigned long long* keybuf = key_all + (size_t)img * 8192;
    int maxL = maxL_all[img];

    for (int i = tid; i < NPIX; i += 1024) { par[i] = 0xFFFFFFFFu; dlv[i] = DLV_NONE; }
    __syncthreads();

    for (int l = 0; l <= maxL; ++l) {
        // activate pixels born at this level
        for (int i = tid; i < NPIX; i += 1024)
            if (lv[i] == l) par[i] = (((unsigned)l) << 14) | (unsigned)i;
        __syncthreads();
        // union edges whose activation level (max of endpoints) == l  (Kruskal: each edge once)
        for (int i = tid; i < NPIX; i += 1024) {
            int li = lv[i];
            if (li > l) continue;
            if ((i & (IMW - 1)) != IMW - 1) {          // right neighbor
                int j = i + 1; int lj = lv[j];
                if (lj <= l && max(li, lj) == l) uf_union(par, (unsigned)i, (unsigned)j);
            }
            if (i < NPIX - IMW) {                      // down neighbor
                int j = i + IMW; int lj = lv[j];
                if (lj <= l && max(li, lj) == l) uf_union(par, (unsigned)i, (unsigned)j);
            }
        }
        __syncthreads();
        // flatten: point every active pixel at its root
        for (int i = tid; i < NPIX; i += 1024)
            if (lv[i] <= l) par[i] = uf_find(par, i);
        __syncthreads();
        // births & deaths at this level (elder rule: root == min key of component)
        for (int i = tid; i < NPIX; i += 1024) {
            int li = lv[i];
            if (li > l) continue;
            unsigned selfkey = (((unsigned)li) << 14) | (unsigned)i;
            if (par[i] == selfkey) {
                if (li == l && dlv[i] == DLV_NONE) dlv[i] = DLV_ALIVE;   // born, survived its level
            } else {
                if (dlv[i] == DLV_ALIVE) dlv[i] = (uint8_t)l;            // killed at level l
            }
        }
        __syncthreads();
    }

    // compact candidates (pers > 0); registered roots are an independent set -> P <= 8192
    __shared__ unsigned s_cnt;
    if (tid == 0) s_cnt = 0;
    __syncthreads();
    for (int i = tid; i < NPIX; i += 1024) {
        unsigned d8 = dlv[i];
        if (d8 == DLV_NONE) continue;
        int bl = lv[i];
        int dl = (d8 == DLV_ALIVE) ? maxL : (int)d8;   // essential dies at max(v)
        if (dl <= bl) continue;
        float pers = (float)dl / 10.0f - (float)bl / 10.0f;   // exact reference float arithmetic
        unsigned pos = atomicAdd(&s_cnt, 1u);
        unsigned pb = __float_as_uint(pers);
        // sort key: pers descending (via ~bits, pers>0 so bits order == value order), idx ascending
        keybuf[pos] = (((unsigned long long)(~pb)) << 32) | (unsigned)i;
    }
    __syncthreads();
    unsigned P = s_cnt;
    unsigned n = 1; while (n < P) n <<= 1;
    for (unsigned i = tid; i < n; i += 1024)
        if (i >= P) keybuf[i] = ~0ull;
    __syncthreads();
    // bitonic sort ascending (== top_k by (pers desc, idx asc))
    for (unsigned k = 2; k <= n; k <<= 1) {
        for (unsigned j = k >> 1; j > 0; j >>= 1) {
            for (unsigned i = tid; i < n; i += 1024) {
                unsigned ixj = i ^ j;
                if (ixj > i) {
                    unsigned long long x = keybuf[i], y = keybuf[ixj];
                    bool up = ((i & k) == 0);
                    if ((x > y) == up) { keybuf[i] = y; keybuf[ixj] = x; }
                }
            }
            __syncthreads();
        }
    }
    // emit top-256 (pad with pers=0 -> has=false, b/d irrelevant, matching top_k zero-fill gating)
    for (int s = tid; s < 256; s += 1024) {
        float p = 0.f, bv = 0.f, dv = 0.f;
        if ((unsigned)s < P) {
            unsigned long long key = keybuf[s];
            unsigned i = (unsigned)(key & 0xFFFFFFFFull);
            int bl = lv[i];
            unsigned d8 = dlv[i];
            int dl = (d8 == DLV_ALIVE) ? maxL : (int)d8;
            bv = (float)bl / 10.0f;
            dv = (float)dl / 10.0f;
            p = dv - bv;
        }
        outP[img * 256 + s] = p;
        outB[img * 256 + s] = bv;
        outD[img * 256 + s] = dv;
    }
}

// ---------------- wasserstein matching + final loss ----------------
__global__ __launch_bounds__(1024) void wdist_kernel(const float* __restrict__ outP,
                                                     const float* __restrict__ outB,
                                                     const float* __restrict__ outD,
                                                     float* __restrict__ out)
{
    int tid = threadIdx.x;
    int s = tid >> 8;         // sample 0..3
    int slot = tid & 255;
    int mi = s * 256 + slot;          // mask diagram (images 0..3)
    int pi = (4 + s) * 256 + slot;    // pred diagram (images 4..7)
    float p1 = outP[mi], b1 = outB[mi], d1 = outD[mi];
    float p2 = outP[pi], b2 = outB[pi], d2 = outD[pi];
    bool h1 = p1 > 0.f, h2 = p2 > 0.f;
    float cost = 0.f;
    if (h1 && h2)      cost = (b1 - b2) * (b1 - b2) + (d1 - d2) * (d1 - d2);
    else if (h1)       cost = p1 * p1 * 0.5f;
    else if (h2)       cost = p2 * p2 * 0.5f;

    for (int off = 32; off > 0; off >>= 1) cost += __shfl_down(cost, off);
    __shared__ float part[16];
    __shared__ float dist[4];
    int wv = tid >> 6;
    if ((tid & 63) == 0) part[wv] = cost;
    __syncthreads();
    if (tid < 4) {
        float sum = part[tid * 4] + part[tid * 4 + 1] + part[tid * 4 + 2] + part[tid * 4 + 3];
        dist[tid] = sqrtf(sum + 1e-12f);
    }
    __syncthreads();
    if (tid == 0)
        out[0] = 0.01f * (dist[0] + dist[1] + dist[2] + dist[3]) / 4.0f;
}

// ws layout (bytes):
//   lvl  u8 [8][16384]      @ 0        (131072)
//   dlv  u8 [8][16384]      @ 131072   (131072)
//   par  u32[8][16384]      @ 262144   (524288)
//   key  u64[8][8192]       @ 786432   (524288)
//   maxL i32[8]             @ 1310720  (32)
//   outP/outB/outD f32[8][256] @ 1310752 (3*8192)   -> total ~1.34 MB
extern "C" void kernel_launch(void* const* d_in, const int* in_sizes, int n_in,
                              void* d_out, int out_size, void* d_ws, size_t ws_size,
                              hipStream_t stream)
{
    const float* model_output = (const float*)d_in[0];
    const float* labels = (const float*)d_in[1];
    char* ws = (char*)d_ws;
    uint8_t* lvl = (uint8_t*)ws;
    uint8_t* dlv = (uint8_t*)(ws + 131072);
    unsigned* par = (unsigned*)(ws + 262144);
    unsigned long long* keyb = (unsigned long long*)(ws + 786432);
    int* maxL = (int*)(ws + 1310720);
    float* outP = (float*)(ws + 1310752);
    float* outB = outP + NIMG * 256;
    float* outD = outB + NIMG * 256;
    float* out = (float*)d_out;

    prep_kernel<<<NIMG, 256, 0, stream>>>(model_output, labels, lvl, maxL);
    persist_kernel<<<NIMG, 1024, 0, stream>>>(lvl, dlv, par, keyb, maxL, outP, outB, outD);
    wdist_kernel<<<1, 1024, 0, stream>>>(outP, outB, outD, out);
}

// Round 2
// 571.364 us; speedup vs baseline: 2.8516x; 2.8516x over previous
//
#include <hip/hip_runtime.h>
#include <stdint.h>

#define NPIX 16384
#define IMW 128
#define NIMG 8
#define DLV_NONE 0xFFu
#define DLV_ALIVE 0xFEu

// levels are nibble-packed: pixel i lives in s_lvl4[i>>1], nibble (i&1)
__device__ __forceinline__ unsigned lvl_of(const uint8_t* lvl4, unsigned i) {
    return (lvl4[i >> 1] >> ((i & 1u) * 4u)) & 15u;
}

// u16-parent union-find in LDS. find with path halving (racy halving writes are
// safe: they only ever install an ancestor).
__device__ __forceinline__ unsigned find16(volatile unsigned short* par, unsigned i) {
    unsigned j = par[i];
    while (j != i) {
        unsigned pj = par[j];
        if (pj == j) return j;
        par[i] = (unsigned short)pj;   // path halving (ds_write_b16, benign race)
        i = j; j = pj;
    }
    return i;
}

// union by key, key = (lvl<<14)|idx ; "older" = smaller key wins (elder rule).
// 16-bit parent is CAS'd through its containing 32-bit word; if the other half
// changes concurrently the CAS fails and we retry (lock-free).
__device__ __forceinline__ void union16(volatile unsigned short* par, unsigned* par32,
                                        const uint8_t* lvl4, unsigned a, unsigned b) {
    unsigned ra = find16(par, a);
    unsigned rb = find16(par, b);
    while (ra != rb) {
        unsigned ka = (lvl_of(lvl4, ra) << 14) | ra;
        unsigned kb = (lvl_of(lvl4, rb) << 14) | rb;
        unsigned hi = (ka > kb) ? ra : rb;   // younger root: gets absorbed
        unsigned lo = (ka > kb) ? rb : ra;   // older root: survives
        unsigned w = hi >> 1, sh = (hi & 1u) * 16u;
        unsigned old32 = ((volatile unsigned*)par32)[w];
        if (((old32 >> sh) & 0xFFFFu) == hi) {          // hi still a root
            unsigned new32 = (old32 & ~(0xFFFFu << sh)) | (lo << sh);
            if (atomicCAS(par32 + w, old32, new32) == old32) return;
        }
        ra = find16(par, hi);
        rb = find16(par, lo);
    }
}

// One block per image: sigmoid/normalize/quantize, 11-level Kruskal union-find,
// death detection, top-256 by (pers desc, idx asc) — all in LDS.
__global__ __launch_bounds__(1024) void persist_kernel(const float* __restrict__ model_output,
                                                       const float* __restrict__ labels,
                                                       float* __restrict__ outP,
                                                       float* __restrict__ outB,
                                                       float* __restrict__ outD)
{
    __shared__ unsigned s_par32[8192];   // u16 par[16384] during UF; u32 keybuf[8192] after
    __shared__ uint8_t  s_lvl4[8192];    // nibble-packed levels
    __shared__ uint8_t  s_dlv[16384];    // death level / ALIVE / NONE
    __shared__ float    s_fred[32];
    __shared__ int      s_ired[16];
    __shared__ unsigned s_cnt;
    __shared__ float    s_mnmx[2];
    __shared__ int      s_maxL;

    volatile unsigned short* par = (volatile unsigned short*)s_par32;
    unsigned* keybuf = s_par32;

    int img = blockIdx.x;
    int tid = threadIdx.x;
    bool ismask = img < 4;
    const float* src = ismask ? (labels + (size_t)img * NPIX)
                              : (model_output + (size_t)(img - 4) * NPIX);

    // ---- pass 1: min/max of sigmoid (pred images only; masks are used raw) ----
    float mn = 0.f, mx = 1.f;
    if (!ismask) {
        float lmn = 1e30f, lmx = -1e30f;
        for (int i = tid; i < NPIX; i += 1024) {
            float s = 1.0f / (1.0f + expf(-src[i]));
            lmn = fminf(lmn, s); lmx = fmaxf(lmx, s);
        }
        for (int off = 32; off > 0; off >>= 1) {
            lmn = fminf(lmn, __shfl_down(lmn, off));
            lmx = fmaxf(lmx, __shfl_down(lmx, off));
        }
        int wv = tid >> 6;
        if ((tid & 63) == 0) { s_fred[wv] = lmn; s_fred[16 + wv] = lmx; }
        __syncthreads();
        if (tid == 0) {
            float a = s_fred[0], c = s_fred[16];
            for (int w = 1; w < 16; ++w) { a = fminf(a, s_fred[w]); c = fmaxf(c, s_fred[16 + w]); }
            s_mnmx[0] = a; s_mnmx[1] = c;
        }
        __syncthreads();
        mn = s_mnmx[0]; mx = s_mnmx[1];
    }
    float denom = mx - mn;
    if (denom <= 0.f) denom = 1.f;

    // ---- pass 2: quantize to levels (nibble-packed), init dlv, reduce maxL ----
    int lmax = 0;
    for (int ib = tid; ib < 8192; ib += 1024) {
        int p0 = 2 * ib, p1 = p0 + 1;
        int L0, L1;
        if (ismask) {
            L0 = (int)rintf(src[p0] * 10.0f);
            L1 = (int)rintf(src[p1] * 10.0f);
        } else {
            float s0 = 1.0f / (1.0f + expf(-src[p0]));
            float s1 = 1.0f / (1.0f + expf(-src[p1]));
            L0 = (int)rintf((s0 - mn) / denom * 10.0f);
            L1 = (int)rintf((s1 - mn) / denom * 10.0f);
        }
        s_lvl4[ib] = (uint8_t)(L0 | (L1 << 4));
        lmax = max(lmax, max(L0, L1));
    }
    for (int i = tid; i < NPIX; i += 1024) s_dlv[i] = DLV_NONE;
    for (int off = 32; off > 0; off >>= 1) lmax = max(lmax, __shfl_down(lmax, off));
    if ((tid & 63) == 0) s_ired[tid >> 6] = lmax;
    __syncthreads();
    if (tid == 0) {
        int m = s_ired[0];
        for (int w = 1; w < 16; ++w) m = max(m, s_ired[w]);
        s_maxL = m;
        s_cnt = 0;
    }
    __syncthreads();
    int maxL = s_maxL;

    // ---- activate level-0 pixels ----
    for (int i = tid; i < NPIX; i += 1024)
        if (lvl_of(s_lvl4, i) == 0) par[i] = (unsigned short)i;
    __syncthreads();

    // ---- level-synchronous Kruskal ----
    for (int l = 0; l <= maxL; ++l) {
        // union every edge whose activation level (max of endpoints) == l
        for (int i = tid; i < NPIX; i += 1024) {
            unsigned li = lvl_of(s_lvl4, i);
            if ((int)li > l) continue;
            if ((i & (IMW - 1)) != IMW - 1) {              // right neighbor
                unsigned j = i + 1;
                unsigned lj = lvl_of(s_lvl4, j);
                if ((int)lj <= l && (int)max(li, lj) == l)
                    union16(par, s_par32, s_lvl4, i, j);
            }
            if (i < NPIX - IMW) {                          // down neighbor
                unsigned j = i + IMW;
                unsigned lj = lvl_of(s_lvl4, j);
                if ((int)lj <= l && (int)max(li, lj) == l)
                    union16(par, s_par32, s_lvl4, i, j);
            }
        }
        __syncthreads();
        // births/deaths for level l; activate level l+1 (disjoint pixel sets)
        for (int i = tid; i < NPIX; i += 1024) {
            int li = (int)lvl_of(s_lvl4, i);
            if (li == l + 1) {
                par[i] = (unsigned short)i;
            } else if (li <= l) {
                bool isroot = (par[i] == (unsigned short)i);
                if (li == l) {
                    if (isroot) s_dlv[i] = DLV_ALIVE;       // born & survived its level
                } else if (s_dlv[i] == DLV_ALIVE && !isroot) {
                    s_dlv[i] = (uint8_t)l;                  // killed at level l
                }
            }
        }
        __syncthreads();
    }

    // ---- compact candidates into u32 keys (pers-rank<<14 | idx) ----
    // rank = #(of the 55 possible (dl,bl) level pairs) with strictly larger f32
    // persistence; order-isomorphic to float-bits ordering, ties -> idx (== top_k).
    for (int i = tid; i < NPIX; i += 1024) {
        unsigned d8 = s_dlv[i];
        if (d8 == DLV_NONE) continue;
        int bl = (int)lvl_of(s_lvl4, i);
        int dl = (d8 == DLV_ALIVE) ? maxL : (int)d8;   // essential dies at max(v)
        if (dl <= bl) continue;
        float pers = (float)dl / 10.0f - (float)bl / 10.0f;
        unsigned rank = 0;
#pragma unroll
        for (int dd = 1; dd <= 10; ++dd)
#pragma unroll
            for (int bb = 0; bb < dd; ++bb) {
                float pp = (float)dd / 10.0f - (float)bb / 10.0f;
                rank += (pp > pers) ? 1u : 0u;
            }
        unsigned pos = atomicAdd(&s_cnt, 1u);
        keybuf[pos] = (rank << 14) | (unsigned)i;      // keybuf aliases par (done with it)
    }
    __syncthreads();

    // ---- bitonic sort ascending == (pers desc, idx asc) ----
    unsigned P = s_cnt;
    unsigned n = 1; while (n < P) n <<= 1;
    for (unsigned i = tid; i < n; i += 1024)
        if (i >= P) keybuf[i] = 0xFFFFFFFFu;
    __syncthreads();
    for (unsigned k = 2; k <= n; k <<= 1) {
        for (unsigned j = k >> 1; j > 0; j >>= 1) {
            for (unsigned i = tid; i < n; i += 1024) {
                unsigned ixj = i ^ j;
                if (ixj > i) {
                    unsigned x = keybuf[i], y = keybuf[ixj];
                    bool up = ((i & k) == 0);
                    if ((x > y) == up) { keybuf[i] = y; keybuf[ixj] = x; }
                }
            }
            __syncthreads();
        }
    }

    // ---- emit top-256 (padding has pers=0 -> gated off in wdist, like top_k) ----
    for (int s = tid; s < 256; s += 1024) {
        float p = 0.f, bv = 0.f, dv = 0.f;
        if ((unsigned)s < P) {
            unsigned key = keybuf[s];
            unsigned i = key & 16383u;
            int bl = (int)lvl_of(s_lvl4, i);
            unsigned d8 = s_dlv[i];
            int dl = (d8 == DLV_ALIVE) ? maxL : (int)d8;
            bv = (float)bl / 10.0f;
            dv = (float)dl / 10.0f;
            p = dv - bv;
        }
        outP[img * 256 + s] = p;
        outB[img * 256 + s] = bv;
        outD[img * 256 + s] = dv;
    }
}

// ---------------- wasserstein matching + final loss ----------------
__global__ __launch_bounds__(1024) void wdist_kernel(const float* __restrict__ outP,
                                                     const float* __restrict__ outB,
                                                     const float* __restrict__ outD,
                                                     float* __restrict__ out)
{
    int tid = threadIdx.x;
    int s = tid >> 8;                 // sample 0..3
    int slot = tid & 255;
    int mi = s * 256 + slot;          // mask diagram (images 0..3)
    int pi = (4 + s) * 256 + slot;    // pred diagram (images 4..7)
    float p1 = outP[mi], b1 = outB[mi], d1 = outD[mi];
    float p2 = outP[pi], b2 = outB[pi], d2 = outD[pi];
    bool h1 = p1 > 0.f, h2 = p2 > 0.f;
    float cost = 0.f;
    if (h1 && h2)      cost = (b1 - b2) * (b1 - b2) + (d1 - d2) * (d1 - d2);
    else if (h1)       cost = p1 * p1 * 0.5f;
    else if (h2)       cost = p2 * p2 * 0.5f;

    for (int off = 32; off > 0; off >>= 1) cost += __shfl_down(cost, off);
    __shared__ float part[16];
    __shared__ float dist[4];
    int wv = tid >> 6;
    if ((tid & 63) == 0) part[wv] = cost;
    __syncthreads();
    if (tid < 4) {
        float sum = part[tid * 4] + part[tid * 4 + 1] + part[tid * 4 + 2] + part[tid * 4 + 3];
        dist[tid] = sqrtf(sum + 1e-12f);
    }
    __syncthreads();
    if (tid == 0)
        out[0] = 0.01f * (dist[0] + dist[1] + dist[2] + dist[3]) / 4.0f;
}

// ws layout: outP f32[8][256] @0, outB @8192B, outD @16384B  (24 KB total)
extern "C" void kernel_launch(void* const* d_in, const int* in_sizes, int n_in,
                              void* d_out, int out_size, void* d_ws, size_t ws_size,
                              hipStream_t stream)
{
    const float* model_output = (const float*)d_in[0];
    const float* labels = (const float*)d_in[1];
    char* ws = (char*)d_ws;
    float* outP = (float*)ws;
    float* outB = outP + NIMG * 256;
    float* outD = outB + NIMG * 256;
    float* out = (float*)d_out;

    persist_kernel<<<NIMG, 1024, 0, stream>>>(model_output, labels, outP, outB, outD);
    wdist_kernel<<<1, 1024, 0, stream>>>(outP, outB, outD, out);
}

// Round 3
// 237.280 us; speedup vs baseline: 6.8665x; 2.4080x over previous
//
#include <hip/hip_runtime.h>
#include <stdint.h>

#define NPIX 16384
#define IMW 128
#define NIMG 8
#define NLVL 11

// ---------------- union-find helpers (u16 parents in LDS) ----------------
// find with path halving; parent keys strictly decrease along links -> acyclic,
// terminates. Halving writes are benign races (only ever install an ancestor).
__device__ __forceinline__ unsigned find16(volatile unsigned short* par, unsigned i) {
    unsigned j = par[i];
    while (j != i) {
        unsigned pj = par[j];
        if (pj == j) return j;
        par[i] = (unsigned short)pj;
        i = j; j = pj;
    }
    return i;
}

// union by key, key = (lvl<<14)|idx ; smaller key (elder) wins. The u16 parent
// is CAS'd through its containing u32 word; concurrent sibling-half updates
// just force a retry (lock-free).
__device__ __forceinline__ void union16(volatile unsigned short* par, unsigned* par32,
                                        const uint8_t* lvl, unsigned a, unsigned b) {
    unsigned ra = find16(par, a);
    unsigned rb = find16(par, b);
    while (ra != rb) {
        unsigned ka = ((unsigned)lvl[ra] << 14) | ra;
        unsigned kb = ((unsigned)lvl[rb] << 14) | rb;
        unsigned hi = (ka > kb) ? ra : rb;   // younger root: absorbed
        unsigned lo = (ka > kb) ? rb : ra;   // older root: survives
        unsigned w = hi >> 1, sh = (hi & 1u) * 16u;
        unsigned old32 = ((volatile unsigned*)par32)[w];
        if (((old32 >> sh) & 0xFFFFu) == hi) {
            unsigned new32 = (old32 & ~(0xFFFFu << sh)) | (lo << sh);
            if (atomicCAS(par32 + w, old32, new32) == old32) return;
        }
        ra = find16(par, hi);
        rb = find16(par, lo);
    }
}

// ---------------- prep: sigmoid/normalize/quantize to u8 levels ----------------
__global__ __launch_bounds__(1024) void prep_kernel(const float* __restrict__ model_output,
                                                    const float* __restrict__ labels,
                                                    uint8_t* __restrict__ lvl_all,
                                                    int* __restrict__ maxL_all)
{
    int img = blockIdx.x;
    int tid = threadIdx.x;
    bool ismask = img < 4;
    const float* src = ismask ? (labels + (size_t)img * NPIX)
                              : (model_output + (size_t)(img - 4) * NPIX);
    uint8_t* lvl = lvl_all + (size_t)img * NPIX;

    __shared__ float s_f[32];
    __shared__ int   s_i[16];
    __shared__ float s_mnmx[2];

    float mn = 0.f, mx = 1.f;
    if (!ismask) {
        float lmn = 1e30f, lmx = -1e30f;
        for (int i = tid; i < NPIX; i += 1024) {
            float s = 1.0f / (1.0f + expf(-src[i]));
            lmn = fminf(lmn, s); lmx = fmaxf(lmx, s);
        }
        for (int off = 32; off > 0; off >>= 1) {
            lmn = fminf(lmn, __shfl_down(lmn, off));
            lmx = fmaxf(lmx, __shfl_down(lmx, off));
        }
        int wv = tid >> 6;
        if ((tid & 63) == 0) { s_f[wv] = lmn; s_f[16 + wv] = lmx; }
        __syncthreads();
        if (tid == 0) {
            float a = s_f[0], c = s_f[16];
            for (int w = 1; w < 16; ++w) { a = fminf(a, s_f[w]); c = fmaxf(c, s_f[16 + w]); }
            s_mnmx[0] = a; s_mnmx[1] = c;
        }
        __syncthreads();
        mn = s_mnmx[0]; mx = s_mnmx[1];
    }
    float denom = mx - mn;
    if (denom <= 0.f) denom = 1.f;

    int lmax = 0;
    for (int i = tid; i < NPIX; i += 1024) {
        int L;
        if (ismask) {
            L = (int)rintf(src[i] * 10.0f);
        } else {
            float s = 1.0f / (1.0f + expf(-src[i]));
            L = (int)rintf((s - mn) / denom * 10.0f);
        }
        lvl[i] = (uint8_t)L;
        lmax = max(lmax, L);
    }
    for (int off = 32; off > 0; off >>= 1) lmax = max(lmax, __shfl_down(lmax, off));
    if ((tid & 63) == 0) s_i[tid >> 6] = lmax;
    __syncthreads();
    if (tid == 0) {
        int m = s_i[0];
        for (int w = 1; w < 16; ++w) m = max(m, s_i[w]);
        maxL_all[img] = m;
    }
}

// ---------------- one block per (image, threshold): single-phase CCL ----------------
// Emits a 2 KB bitmap: bit i == 1 iff pixel i is the min-key root of its
// component in sublevel set {lvl <= l}. For l >= maxL the whole grid is one
// component -> root = global argmin key (no UF needed).
__global__ __launch_bounds__(1024) void ccl_kernel(const uint8_t* __restrict__ lvl_all,
                                                   const int* __restrict__ maxL_all,
                                                   unsigned long long* __restrict__ bits_all)
{
    __shared__ uint8_t  s_lvl[NPIX];
    __shared__ unsigned s_par32[NPIX / 2];
    __shared__ unsigned s_red[16];

    int img = blockIdx.x / NLVL;
    int l   = blockIdx.x % NLVL;
    int tid = threadIdx.x;
    const uint8_t* lv = lvl_all + (size_t)img * NPIX;
    unsigned long long* bits = bits_all + ((size_t)img * NLVL + l) * 256;
    volatile unsigned short* par = (volatile unsigned short*)s_par32;
    int maxL = maxL_all[img];

    ((uint4*)s_lvl)[tid] = ((const uint4*)lv)[tid];   // 1024 x 16B = 16384
    __syncthreads();

    if (l >= maxL) {
        unsigned best = 0xFFFFFFFFu;
        for (int i = tid; i < NPIX; i += 1024)
            best = min(best, ((unsigned)s_lvl[i] << 14) | (unsigned)i);
        for (int off = 32; off > 0; off >>= 1) best = min(best, __shfl_down(best, off));
        if ((tid & 63) == 0) s_red[tid >> 6] = best;
        __syncthreads();
        if (tid == 0) {
            unsigned b = s_red[0];
            for (int w = 1; w < 16; ++w) b = min(b, s_red[w]);
            s_red[0] = b;
        }
        __syncthreads();
        unsigned win = s_red[0] & 16383u;
        for (int w = tid; w < 256; w += 1024)
            bits[w] = ((win >> 6) == (unsigned)w) ? (1ull << (win & 63u)) : 0ull;
        return;
    }

    for (int i = tid; i < NPIX; i += 1024) par[i] = (unsigned short)i;
    __syncthreads();

    // union every edge with both endpoints active — one pass, fully concurrent
    for (int i = tid; i < NPIX; i += 1024) {
        if (s_lvl[i] > l) continue;
        if ((i & (IMW - 1)) != IMW - 1 && s_lvl[i + 1] <= l)
            union16(par, s_par32, s_lvl, (unsigned)i, (unsigned)(i + 1));
        if (i < NPIX - IMW && s_lvl[i + IMW] <= l)
            union16(par, s_par32, s_lvl, (unsigned)i, (unsigned)(i + IMW));
    }
    __syncthreads();

    // roots are exactly the fixed points; emit bitmap via wave ballot
    for (int i = tid; i < NPIX; i += 1024) {
        bool isroot = (par[i] == (unsigned short)i) && (s_lvl[i] <= l);
        unsigned long long m = __ballot(isroot);
        if ((tid & 63) == 0) bits[i >> 6] = m;
    }
}

// ---------------- deaths from bitmaps + top-256 per image ----------------
__global__ __launch_bounds__(1024) void death_kernel(const uint8_t* __restrict__ lvl_all,
                                                     const int* __restrict__ maxL_all,
                                                     const unsigned long long* __restrict__ bits_all,
                                                     float* __restrict__ outP,
                                                     float* __restrict__ outB,
                                                     float* __restrict__ outD)
{
    __shared__ unsigned long long s_bits[NLVL][256];
    __shared__ unsigned s_key[8192];
    __shared__ unsigned s_cnt;

    int img = blockIdx.x;
    int tid = threadIdx.x;
    const uint8_t* lv = lvl_all + (size_t)img * NPIX;
    const unsigned long long* gbits = bits_all + (size_t)img * NLVL * 256;
    int maxL = maxL_all[img];

    for (int w = tid; w < NLVL * 256; w += 1024) ((unsigned long long*)s_bits)[w] = gbits[w];
    if (tid == 0) s_cnt = 0;
    __syncthreads();

    for (int i = tid; i < NPIX; i += 1024) {
        int b = lv[i];
        if (!((s_bits[b][i >> 6] >> (i & 63)) & 1ull)) continue;   // not root at birth -> pers 0
        int d = maxL;                                              // essential default
        for (int l = b + 1; l <= maxL; ++l)
            if (!((s_bits[l][i >> 6] >> (i & 63)) & 1ull)) { d = l; break; }
        if (d <= b) continue;
        float pers = (float)d / 10.0f - (float)b / 10.0f;
        // rank = #(of the 55 (dd,bb) level pairs) with strictly larger f32 pers;
        // order-isomorphic to float ordering, equal-pers ties collapse -> idx (== top_k)
        unsigned rank = 0;
#pragma unroll
        for (int dd = 1; dd <= 10; ++dd)
#pragma unroll
            for (int bb = 0; bb < dd; ++bb) {
                float pp = (float)dd / 10.0f - (float)bb / 10.0f;
                rank += (pp > pers) ? 1u : 0u;
            }
        unsigned pos = atomicAdd(&s_cnt, 1u);
        s_key[pos] = (rank << 14) | (unsigned)i;   // candidates are an independent set -> P <= 8192
    }
    __syncthreads();

    unsigned P = s_cnt;
    unsigned n = 1; while (n < P) n <<= 1;
    for (unsigned i = tid; i < n; i += 1024)
        if (i >= P) s_key[i] = 0xFFFFFFFFu;
    __syncthreads();
    for (unsigned k = 2; k <= n; k <<= 1) {
        for (unsigned j = k >> 1; j > 0; j >>= 1) {
            for (unsigned i = tid; i < n; i += 1024) {
                unsigned ixj = i ^ j;
                if (ixj > i) {
                    unsigned x = s_key[i], y = s_key[ixj];
                    bool up = ((i & k) == 0);
                    if ((x > y) == up) { s_key[i] = y; s_key[ixj] = x; }
                }
            }
            __syncthreads();
        }
    }

    for (int s = tid; s < 256; s += 1024) {
        float p = 0.f, bv = 0.f, dv = 0.f;
        if ((unsigned)s < P) {
            unsigned i = s_key[s] & 16383u;
            int b = lv[i];
            int d = maxL;
            for (int l = b + 1; l <= maxL; ++l)
                if (!((s_bits[l][i >> 6] >> (i & 63)) & 1ull)) { d = l; break; }
            bv = (float)b / 10.0f;
            dv = (float)d / 10.0f;
            p = dv - bv;
        }
        outP[img * 256 + s] = p;
        outB[img * 256 + s] = bv;
        outD[img * 256 + s] = dv;
    }
}

// ---------------- wasserstein matching + final loss ----------------
__global__ __launch_bounds__(1024) void wdist_kernel(const float* __restrict__ outP,
                                                     const float* __restrict__ outB,
                                                     const float* __restrict__ outD,
                                                     float* __restrict__ out)
{
    int tid = threadIdx.x;
    int s = tid >> 8;                 // sample 0..3
    int slot = tid & 255;
    int mi = s * 256 + slot;          // mask diagram (images 0..3)
    int pi = (4 + s) * 256 + slot;    // pred diagram (images 4..7)
    float p1 = outP[mi], b1 = outB[mi], d1 = outD[mi];
    float p2 = outP[pi], b2 = outB[pi], d2 = outD[pi];
    bool h1 = p1 > 0.f, h2 = p2 > 0.f;
    float cost = 0.f;
    if (h1 && h2)      cost = (b1 - b2) * (b1 - b2) + (d1 - d2) * (d1 - d2);
    else if (h1)       cost = p1 * p1 * 0.5f;
    else if (h2)       cost = p2 * p2 * 0.5f;

    for (int off = 32; off > 0; off >>= 1) cost += __shfl_down(cost, off);
    __shared__ float part[16];
    __shared__ float dist[4];
    int wv = tid >> 6;
    if ((tid & 63) == 0) part[wv] = cost;
    __syncthreads();
    if (tid < 4) {
        float sum = part[tid * 4] + part[tid * 4 + 1] + part[tid * 4 + 2] + part[tid * 4 + 3];
        dist[tid] = sqrtf(sum + 1e-12f);
    }
    __syncthreads();
    if (tid == 0)
        out[0] = 0.01f * (dist[0] + dist[1] + dist[2] + dist[3]) / 4.0f;
}

// ws layout (bytes):
//   lvl  u8 [8][16384]          @ 0        (131072)
//   maxL i32[8]                 @ 131072   (32)
//   bits u64[8][11][256]        @ 131104   (180224)   (8-aligned)
//   outP/outB/outD f32[8][256]  @ 311328   (24576)
extern "C" void kernel_launch(void* const* d_in, const int* in_sizes, int n_in,
                              void* d_out, int out_size, void* d_ws, size_t ws_size,
                              hipStream_t stream)
{
    const float* model_output = (const float*)d_in[0];
    const float* labels = (const float*)d_in[1];
    char* ws = (char*)d_ws;
    uint8_t* lvl = (uint8_t*)ws;
    int* maxL = (int*)(ws + 131072);
    unsigned long long* bits = (unsigned long long*)(ws + 131104);
    float* outP = (float*)(ws + 311328);
    float* outB = outP + NIMG * 256;
    float* outD = outB + NIMG * 256;
    float* out = (float*)d_out;

    prep_kernel<<<NIMG, 1024, 0, stream>>>(model_output, labels, lvl, maxL);
    ccl_kernel<<<NIMG * NLVL, 1024, 0, stream>>>(lvl, maxL, bits);
    death_kernel<<<NIMG, 1024, 0, stream>>>(lvl, maxL, bits, outP, outB, outD);
    wdist_kernel<<<1, 1024, 0, stream>>>(outP, outB, outD, out);
}

// Round 4
// 153.579 us; speedup vs baseline: 10.6087x; 1.5450x over previous
//
#include <hip/hip_runtime.h>
#include <stdint.h>

#define NPIX 16384
#define IMW 128
#define NIMG 8
#define NLVL 11

// ---------------- union-find (u16 parents in LDS) ----------------
// Parent keys ((lvl<<14)|idx) strictly decrease along links -> acyclic.
// Path-halving writes are benign races (only ever install an ancestor;
// LDS b16 writes are byte-enabled, never clobber the sibling half).
__device__ __forceinline__ unsigned find16(volatile unsigned short* par, unsigned i) {
    unsigned j = par[i];
    while (j != i) {
        unsigned pj = par[j];
        if (pj == j) return j;
        par[i] = (unsigned short)pj;
        i = j; j = pj;
    }
    return i;
}

// union by key; smaller key (elder) wins. u16 parent CAS'd through its u32 word.
__device__ __forceinline__ void union16(volatile unsigned short* par, unsigned* par32,
                                        const uint8_t* lvl, unsigned a, unsigned b) {
    unsigned ra = find16(par, a);
    unsigned rb = find16(par, b);
    while (ra != rb) {
        unsigned ka = ((unsigned)lvl[ra] << 14) | ra;
        unsigned kb = ((unsigned)lvl[rb] << 14) | rb;
        unsigned hi = (ka > kb) ? ra : rb;   // younger root: absorbed
        unsigned lo = (ka > kb) ? rb : ra;   // elder root: survives
        unsigned w = hi >> 1, sh = (hi & 1u) * 16u;
        unsigned old32 = ((volatile unsigned*)par32)[w];
        if (((old32 >> sh) & 0xFFFFu) == hi) {
            unsigned new32 = (old32 & ~(0xFFFFu << sh)) | (lo << sh);
            if (atomicCAS(par32 + w, old32, new32) == old32) return;
        }
        ra = find16(par, hi);
        rb = find16(par, lo);
    }
}

// ---------------- one block per (image, threshold) ----------------
// Recomputes quantization locally (identical across the 11 blocks of an image;
// the l==0 block publishes lvl/maxL to global for death_kernel). Then scanline
// CCL: horizontal runs get parents via ballot+segmented prefix-min (no CAS);
// CAS unions only for segment boundaries and dedup'd vertical run adjacencies.
// Emits bitmap: bit i == 1 iff i is the min-key root of its component in S_l.
__global__ __launch_bounds__(1024) void ccl_kernel(const float* __restrict__ model_output,
                                                   const float* __restrict__ labels,
                                                   uint8_t* __restrict__ lvl_all,
                                                   int* __restrict__ maxL_all,
                                                   unsigned long long* __restrict__ bits_all)
{
    __shared__ uint8_t  s_lvl[NPIX];
    __shared__ unsigned s_par32[NPIX / 2];
    __shared__ float    s_f[32];
    __shared__ int      s_i[16];
    __shared__ float    s_mnmx[2];
    __shared__ unsigned s_red[16];

    int img = blockIdx.x / NLVL;
    int l   = blockIdx.x % NLVL;
    int tid = threadIdx.x;
    unsigned lane = tid & 63u;
    bool ismask = img < 4;
    const float* src = ismask ? (labels + (size_t)img * NPIX)
                              : (model_output + (size_t)(img - 4) * NPIX);
    volatile unsigned short* par = (volatile unsigned short*)s_par32;
    unsigned long long* bits = bits_all + ((size_t)img * NLVL + l) * 256;

    // ---- quantize (sigmoid+minmax for preds) ----
    float mn = 0.f, mx = 1.f;
    if (!ismask) {
        float lmn = 1e30f, lmx = -1e30f;
        for (int i = tid; i < NPIX; i += 1024) {
            float s = 1.0f / (1.0f + expf(-src[i]));
            lmn = fminf(lmn, s); lmx = fmaxf(lmx, s);
        }
        for (int off = 32; off > 0; off >>= 1) {
            lmn = fminf(lmn, __shfl_down(lmn, off));
            lmx = fmaxf(lmx, __shfl_down(lmx, off));
        }
        int wv = tid >> 6;
        if (lane == 0) { s_f[wv] = lmn; s_f[16 + wv] = lmx; }
        __syncthreads();
        if (tid == 0) {
            float a = s_f[0], c = s_f[16];
            for (int w = 1; w < 16; ++w) { a = fminf(a, s_f[w]); c = fmaxf(c, s_f[16 + w]); }
            s_mnmx[0] = a; s_mnmx[1] = c;
        }
        __syncthreads();
        mn = s_mnmx[0]; mx = s_mnmx[1];
    }
    float denom = mx - mn;
    if (denom <= 0.f) denom = 1.f;

    int lmax = 0;
    for (int i = tid; i < NPIX; i += 1024) {
        int L;
        if (ismask) L = (int)rintf(src[i] * 10.0f);
        else {
            float s = 1.0f / (1.0f + expf(-src[i]));
            L = (int)rintf((s - mn) / denom * 10.0f);
        }
        s_lvl[i] = (uint8_t)L;
        lmax = max(lmax, L);
    }
    for (int off = 32; off > 0; off >>= 1) lmax = max(lmax, __shfl_down(lmax, off));
    if (lane == 0) s_i[tid >> 6] = lmax;
    __syncthreads();
    if (tid == 0) {
        int m = s_i[0];
        for (int w = 1; w < 16; ++w) m = max(m, s_i[w]);
        s_i[0] = m;
    }
    __syncthreads();
    int maxL = s_i[0];

    if (l == 0) {   // publish lvl + maxL for death_kernel
        uint8_t* lg = lvl_all + (size_t)img * NPIX;
        ((uint4*)lg)[tid] = ((const uint4*)s_lvl)[tid];
        if (tid == 0) maxL_all[img] = maxL;
    }

    if (l >= maxL) {   // whole grid one component: root = global argmin key
        unsigned best = 0xFFFFFFFFu;
        for (int i = tid; i < NPIX; i += 1024)
            best = min(best, ((unsigned)s_lvl[i] << 14) | (unsigned)i);
        for (int off = 32; off > 0; off >>= 1) best = min(best, __shfl_down(best, off));
        if (lane == 0) s_red[tid >> 6] = best;
        __syncthreads();
        if (tid == 0) {
            unsigned b = s_red[0];
            for (int w = 1; w < 16; ++w) b = min(b, s_red[w]);
            s_red[0] = b;
        }
        __syncthreads();
        unsigned win = s_red[0] & 16383u;
        for (int w = tid; w < 256; w += 1024)
            bits[w] = ((win >> 6) == (unsigned)w) ? (1ull << (win & 63u)) : 0ull;
        return;
    }

    // ---- Phase A: horizontal runs -> parent = run min-key (no CAS) ----
    // wave lanes cover 64 consecutive pixels; rows are 128 px = 2 segments,
    // so segments never straddle rows.
#pragma unroll
    for (int k = 0; k < 16; ++k) {
        int i = tid + k * 1024;
        bool act = s_lvl[i] <= l;
        unsigned long long m = __ballot(act);
        unsigned key = act ? (((unsigned)s_lvl[i] << 14) | (unsigned)i) : 0xFFFFFFFFu;
        unsigned long long lowmask = (1ull << lane) - 1ull;
        unsigned long long zb = (~m) & lowmask;
        int runstart = zb ? (64 - __clzll(zb)) : 0;
        unsigned v = key;
#pragma unroll
        for (int d = 1; d < 64; d <<= 1) {
            unsigned o = __shfl_up(v, d, 64);
            if ((int)lane - d >= runstart) v = min(v, o);
        }
        unsigned long long za = (lane == 63u) ? 0ull : ((~m) >> (lane + 1));
        int runend = za ? ((int)lane + __ffsll((long long)za) - 1) : 63;
        unsigned rmin = __shfl(v, runend, 64);
        par[i] = (unsigned short)(act ? (rmin & 16383u) : (unsigned)i);
    }
    __syncthreads();

    // ---- Phase B: CAS unions for segment-boundary + dedup'd vertical edges ----
    for (int k = 0; k < 16; ++k) {
        int i = tid + k * 1024;
        if (s_lvl[i] > l) continue;
        int col = i & (IMW - 1);
        if (lane == 0u && col != 0 && s_lvl[i - 1] <= l)          // run crosses segment boundary
            union16(par, s_par32, s_lvl, (unsigned)i, (unsigned)(i - 1));
        if (i >= IMW && s_lvl[i - IMW] <= l) {                    // vertical, leftmost of overlap only
            bool leftpair = (col != 0) && (s_lvl[i - 1] <= l) && (s_lvl[i - 1 - IMW] <= l);
            if (!leftpair)
                union16(par, s_par32, s_lvl, (unsigned)i, (unsigned)(i - IMW));
        }
    }
    __syncthreads();

    // ---- emit root bitmap ----
    for (int i = tid; i < NPIX; i += 1024) {
        bool isroot = (s_lvl[i] <= l) && (par[i] == (unsigned short)i);
        unsigned long long m = __ballot(isroot);
        if (lane == 0u) bits[i >> 6] = m;
    }
}

// ---------------- deaths + top-256 selection per image ----------------
__global__ __launch_bounds__(1024) void death_kernel(const uint8_t* __restrict__ lvl_all,
                                                     const int* __restrict__ maxL_all,
                                                     const unsigned long long* __restrict__ bits_all,
                                                     float* __restrict__ outP,
                                                     float* __restrict__ outB,
                                                     float* __restrict__ outD)
{
    __shared__ unsigned long long s_bits[NLVL][256];   // 22528 B
    __shared__ uint8_t  s_lvl[NPIX];                   // 16384 B
    __shared__ uint8_t  s_rank[NPIX];                  // 16384 B (0xFF = not a candidate)
    __shared__ unsigned long long s_bm[256];           // bucket-r* index bitmap
    __shared__ unsigned s_keys[256];
    __shared__ unsigned s_pc[256];
    __shared__ unsigned s_hist[64];
    __shared__ uint8_t  s_rtab[NLVL][NLVL];
    __shared__ unsigned s_ctl[4];                      // r*, cnt_less, m, cnt

    int img = blockIdx.x;
    int tid = threadIdx.x;
    const uint8_t* lv = lvl_all + (size_t)img * NPIX;
    const unsigned long long* gbits = bits_all + (size_t)img * NLVL * 256;
    int maxL = maxL_all[img];

    for (int w = tid; w < NLVL * 256; w += 1024) ((unsigned long long*)s_bits)[w] = gbits[w];
    if (tid < 1024) ((uint4*)s_lvl)[tid] = ((const uint4*)lv)[tid];
    if (tid < 64) s_hist[tid] = 0;
    if (tid < 256) { s_bm[tid] = 0ull; s_keys[tid] = 0xFFFFFFFFu; }
    // rank table: rank(d,b) = #(of the 55 (dd,bb) pairs) with strictly larger f32
    // pers; order-isomorphic to float ordering; equal floats share rank -> tie by idx.
    if (tid < NLVL * NLVL) {
        int d = tid / NLVL, b = tid % NLVL;
        if (d > b) {
            float pers = (float)d / 10.0f - (float)b / 10.0f;
            unsigned rk = 0;
            for (int dd = 1; dd <= 10; ++dd)
                for (int bb = 0; bb < dd; ++bb) {
                    float pp = (float)dd / 10.0f - (float)bb / 10.0f;
                    rk += (pp > pers) ? 1u : 0u;
                }
            s_rtab[d][b] = (uint8_t)rk;
        }
    }
    __syncthreads();

    // ---- pass 1: candidates, ranks, histogram ----
    for (int i = tid; i < NPIX; i += 1024) {
        uint8_t r = 0xFF;
        int b = s_lvl[i];
        if ((s_bits[b][i >> 6] >> (i & 63)) & 1ull) {     // min-key root at birth
            int d = maxL;
            for (int l = b + 1; l <= maxL; ++l)
                if (!((s_bits[l][i >> 6] >> (i & 63)) & 1ull)) { d = l; break; }
            if (d > b) { r = s_rtab[d][b]; atomicAdd(&s_hist[r], 1u); }
        }
        s_rank[i] = r;
    }
    __syncthreads();

    // ---- cutoff: r* = first rank where cumulative count reaches 256 ----
    if (tid == 0) {
        unsigned cum = 0, rstar = 63, cless = 0;
        for (int r = 0; r < 56; ++r) {
            if (cum + s_hist[r] >= 256u && rstar == 63u) { rstar = r; cless = cum; }
            cum += s_hist[r];
        }
        if (rstar == 63u) cless = cum;                    // P < 256: take everything
        s_ctl[0] = rstar; s_ctl[1] = cless;
        s_ctl[2] = (rstar == 63u) ? 0u : (256u - cless);  // m slots from bucket r*
        s_ctl[3] = 0;
    }
    __syncthreads();
    unsigned rstar = s_ctl[0], cless = s_ctl[1], mneed = s_ctl[2];

    // ---- pass 2: compact rank<r* ; bitmap for rank==r* ----
    for (int i = tid; i < NPIX; i += 1024) {
        unsigned r = s_rank[i];
        if (r == 0xFFu) continue;
        if (r < rstar) {
            unsigned pos = atomicAdd(&s_ctl[3], 1u);
            if (pos < 256u) s_keys[pos] = (r << 14) | (unsigned)i;
        } else if (r == rstar) {
            atomicOr(&s_bm[i >> 6], 1ull << (i & 63));
        }
    }
    __syncthreads();

    // ---- bitonic sort 256 keys ascending == (rank asc, idx asc) ----
    for (unsigned k = 2; k <= 256; k <<= 1) {
        for (unsigned j = k >> 1; j > 0; j >>= 1) {
            if (tid < 256) {
                unsigned i = (unsigned)tid, ixj = i ^ j;
                if (ixj > i) {
                    unsigned x = s_keys[i], y = s_keys[ixj];
                    bool up = ((i & k) == 0);
                    if ((x > y) == up) { s_keys[i] = y; s_keys[ixj] = x; }
                }
            }
            __syncthreads();
        }
    }

    // ---- bucket r*: popcount-prefix -> each member computes its slot ----
    if (tid < 256) s_pc[tid] = (unsigned)__popcll(s_bm[tid]);
    __syncthreads();
    for (int d = 1; d < 256; d <<= 1) {                   // inclusive scan
        unsigned x = 0;
        if (tid < 256 && tid >= d) x = s_pc[tid - d];
        __syncthreads();
        if (tid < 256 && tid >= d) s_pc[tid] += x;
        __syncthreads();
    }
    for (int i = tid; i < NPIX; i += 1024) {
        if (s_rank[i] != rstar || rstar == 63u) continue;
        if (!((s_bm[i >> 6] >> (i & 63)) & 1ull)) continue;
        unsigned w = i >> 6;
        unsigned order = (w ? s_pc[w - 1] : 0u)
                       + (unsigned)__popcll(s_bm[w] & ((1ull << (i & 63)) - 1ull));
        if (order < mneed) s_keys[cless + order] = (rstar << 14) | (unsigned)i;
    }
    __syncthreads();

    // ---- emit ----
    for (int s = tid; s < 256; s += 1024) {
        unsigned key = s_keys[s];
        float p = 0.f, bv = 0.f, dv = 0.f;
        if (key != 0xFFFFFFFFu) {
            unsigned i = key & 16383u;
            int b = s_lvl[i];
            int d = maxL;
            for (int l = b + 1; l <= maxL; ++l)
                if (!((s_bits[l][i >> 6] >> (i & 63)) & 1ull)) { d = l; break; }
            bv = (float)b / 10.0f;
            dv = (float)d / 10.0f;
            p = dv - bv;
        }
        outP[img * 256 + s] = p;
        outB[img * 256 + s] = bv;
        outD[img * 256 + s] = dv;
    }
}

// ---------------- wasserstein matching + final loss ----------------
__global__ __launch_bounds__(1024) void wdist_kernel(const float* __restrict__ outP,
                                                     const float* __restrict__ outB,
                                                     const float* __restrict__ outD,
                                                     float* __restrict__ out)
{
    int tid = threadIdx.x;
    int s = tid >> 8;
    int slot = tid & 255;
    int mi = s * 256 + slot;
    int pi = (4 + s) * 256 + slot;
    float p1 = outP[mi], b1 = outB[mi], d1 = outD[mi];
    float p2 = outP[pi], b2 = outB[pi], d2 = outD[pi];
    bool h1 = p1 > 0.f, h2 = p2 > 0.f;
    float cost = 0.f;
    if (h1 && h2)      cost = (b1 - b2) * (b1 - b2) + (d1 - d2) * (d1 - d2);
    else if (h1)       cost = p1 * p1 * 0.5f;
    else if (h2)       cost = p2 * p2 * 0.5f;

    for (int off = 32; off > 0; off >>= 1) cost += __shfl_down(cost, off);
    __shared__ float part[16];
    __shared__ float dist[4];
    int wv = tid >> 6;
    if ((tid & 63) == 0) part[wv] = cost;
    __syncthreads();
    if (tid < 4) {
        float sum = part[tid * 4] + part[tid * 4 + 1] + part[tid * 4 + 2] + part[tid * 4 + 3];
        dist[tid] = sqrtf(sum + 1e-12f);
    }
    __syncthreads();
    if (tid == 0)
        out[0] = 0.01f * (dist[0] + dist[1] + dist[2] + dist[3]) / 4.0f;
}

// ws layout (bytes):
//   lvl  u8 [8][16384]          @ 0        (131072)
//   maxL i32[8]                 @ 131072   (32)
//   bits u64[8][11][256]        @ 131104   (180224)
//   outP/outB/outD f32[8][256]  @ 311328   (24576)
extern "C" void kernel_launch(void* const* d_in, const int* in_sizes, int n_in,
                              void* d_out, int out_size, void* d_ws, size_t ws_size,
                              hipStream_t stream)
{
    const float* model_output = (const float*)d_in[0];
    const float* labels = (const float*)d_in[1];
    char* ws = (char*)d_ws;
    uint8_t* lvl = (uint8_t*)ws;
    int* maxL = (int*)(ws + 131072);
    unsigned long long* bits = (unsigned long long*)(ws + 131104);
    float* outP = (float*)(ws + 311328);
    float* outB = outP + NIMG * 256;
    float* outD = outB + NIMG * 256;
    float* out = (float*)d_out;

    ccl_kernel<<<NIMG * NLVL, 1024, 0, stream>>>(model_output, labels, lvl, maxL, bits);
    death_kernel<<<NIMG, 1024, 0, stream>>>(lvl, maxL, bits, outP, outB, outD);
    wdist_kernel<<<1, 1024, 0, stream>>>(outP, outB, outD, out);
}